// Round 1
// baseline (1676.076 us; speedup 1.0000x reference)
//
#include <hip/hip_runtime.h>
#include <hip/hip_bf16.h>

#define IGNORE_INDEX (-100)

using f32x4  = __attribute__((ext_vector_type(4))) float;
using bf16x8 = __attribute__((ext_vector_type(8))) short;

constexpr int BM = 256, BN = 256, BK = 64;
constexpr int MT = 8;      // m tiles (2048 padded / 256)
constexpr int NT = 500;    // n tiles (128000 / 256)
constexpr int KT = 32;     // k tiles (2048 / 64)
constexpr int SROWS = 2047;
constexpr int DDIM = 2048;

__device__ __forceinline__ unsigned cvt_pk_bf16(float lo, float hi) {
    unsigned r;
    asm("v_cvt_pk_bf16_f32 %0, %1, %2" : "=v"(r) : "v"(lo), "v"(hi));
    return r;
}

__global__ __launch_bounds__(512, 2)
void ce_fused_gemm(const float* __restrict__ emb,
                   const float* __restrict__ W,
                   const float* __restrict__ bias,
                   const int* __restrict__ labels,
                   float* __restrict__ sumexp,
                   float* __restrict__ tgt)
{
    __shared__ __align__(16) unsigned short As[2][BM * BK];
    __shared__ __align__(16) unsigned short Bs[2][BN * BK];

    // XCD-chunked swizzle: 4000 wgs, 8 XCDs, 500 per XCD.
    // Consecutive logical ids share an n-tile (same W slice) -> L2 reuse.
    const int bid = blockIdx.x;
    const int L = (bid & 7) * (MT * NT / 8) + (bid >> 3);
    const int n_tile = L >> 3;
    const int m_tile = L & 7;
    const size_t m_base = (size_t)m_tile * BM;
    const size_t n_base = (size_t)n_tile * BN;

    const int tid  = threadIdx.x;
    const int lane = tid & 63;
    const int wave = tid >> 6;
    const int wm = wave >> 2;   // 0..1  (row group of 128)
    const int wn = wave & 3;    // 0..3  (col group of 64)
    const int q = lane & 15;
    const int g = lane >> 4;

    const int r0 = tid >> 3;    // 0..63 (staging row)
    const int kg = tid & 7;     // 0..7  (staging k-group of 8 floats)

    float4 stA[4][2], stB[4][2];
    f32x4 acc[8][4];
#pragma unroll
    for (int i = 0; i < 8; ++i)
#pragma unroll
        for (int j = 0; j < 4; ++j)
            acc[i][j] = (f32x4){0.f, 0.f, 0.f, 0.f};

    const float* Ab = emb + m_base * DDIM + (size_t)kg * 8;
    const float* Bb = W   + n_base * DDIM + (size_t)kg * 8;

#define STAGE_LOAD(kt_) { \
    const size_t ko = (size_t)(kt_) * BK; \
    _Pragma("unroll") \
    for (int p = 0; p < 4; ++p) { \
        const int row = r0 + p * 64; \
        const float4* pa = (const float4*)(Ab + (size_t)row * DDIM + ko); \
        stA[p][0] = pa[0]; stA[p][1] = pa[1]; \
        const float4* pb = (const float4*)(Bb + (size_t)row * DDIM + ko); \
        stB[p][0] = pb[0]; stB[p][1] = pb[1]; \
    } }

#define STAGE_WRITE(bf_) { \
    _Pragma("unroll") \
    for (int p = 0; p < 4; ++p) { \
        const int row = r0 + p * 64; \
        const int sw = (kg * 8) ^ ((row & 7) << 3); \
        uint4 ua; \
        ua.x = cvt_pk_bf16(stA[p][0].x, stA[p][0].y); \
        ua.y = cvt_pk_bf16(stA[p][0].z, stA[p][0].w); \
        ua.z = cvt_pk_bf16(stA[p][1].x, stA[p][1].y); \
        ua.w = cvt_pk_bf16(stA[p][1].z, stA[p][1].w); \
        *(uint4*)&As[bf_][row * BK + sw] = ua; \
        uint4 ub; \
        ub.x = cvt_pk_bf16(stB[p][0].x, stB[p][0].y); \
        ub.y = cvt_pk_bf16(stB[p][0].z, stB[p][0].w); \
        ub.z = cvt_pk_bf16(stB[p][1].x, stB[p][1].y); \
        ub.w = cvt_pk_bf16(stB[p][1].z, stB[p][1].w); \
        *(uint4*)&Bs[bf_][row * BK + sw] = ub; \
    } }

#define COMPUTE(bf_) { \
    _Pragma("unroll") \
    for (int kh = 0; kh < 2; ++kh) { \
        const int c = kh * 32 + g * 8; \
        bf16x8 bfr[4]; \
        _Pragma("unroll") \
        for (int nf = 0; nf < 4; ++nf) { \
            const int r = wn * 64 + nf * 16 + q; \
            bfr[nf] = *(const bf16x8*)&Bs[bf_][r * BK + (c ^ ((r & 7) << 3))]; \
        } \
        _Pragma("unroll") \
        for (int mf = 0; mf < 8; ++mf) { \
            const int r = wm * 128 + mf * 16 + q; \
            bf16x8 afr = *(const bf16x8*)&As[bf_][r * BK + (c ^ ((r & 7) << 3))]; \
            _Pragma("unroll") \
            for (int nf = 0; nf < 4; ++nf) \
                acc[mf][nf] = __builtin_amdgcn_mfma_f32_16x16x32_bf16(afr, bfr[nf], acc[mf][nf], 0, 0, 0); \
        } \
    } }

    STAGE_LOAD(0);
    STAGE_WRITE(0);
    __syncthreads();

    int buf = 0;
    for (int kt = 0; kt < KT; ++kt) {
        if (kt + 1 < KT) STAGE_LOAD(kt + 1);
        COMPUTE(buf);
        if (kt + 1 < KT) STAGE_WRITE(buf ^ 1);
        __syncthreads();
        buf ^= 1;
    }

    // ---- epilogue: bias + exp + row-sum + target gather, no scores to HBM ----
    const int grow_base = (int)m_base + wm * 128;
    const int gcol_base = (int)n_base + wn * 64;
#pragma unroll
    for (int mf = 0; mf < 8; ++mf) {
        const int rb = grow_base + mf * 16 + g * 4;   // rows rb+0..rb+3
        int lbl[4];
#pragma unroll
        for (int r = 0; r < 4; ++r)
            lbl[r] = (rb + r < SROWS) ? labels[rb + r + 1] : -1;
        float rsum[4] = {0.f, 0.f, 0.f, 0.f};
#pragma unroll
        for (int nf = 0; nf < 4; ++nf) {
            const int gc = gcol_base + nf * 16 + q;
            const float bz = bias[gc];
            const f32x4 v = acc[mf][nf];
#pragma unroll
            for (int r = 0; r < 4; ++r) {
                const float s = v[r] + bz;
                if (lbl[r] == gc) atomicAdd(&tgt[rb + r], s);
                rsum[r] += __expf(s);
            }
        }
#pragma unroll
        for (int r = 0; r < 4; ++r) {
#pragma unroll
            for (int off = 1; off < 16; off <<= 1)
                rsum[r] += __shfl_xor(rsum[r], off);
        }
        if (q == 0) {
#pragma unroll
            for (int r = 0; r < 4; ++r)
                if (rb + r < SROWS) atomicAdd(&sumexp[rb + r], rsum[r]);
        }
    }
#undef STAGE_LOAD
#undef STAGE_WRITE
#undef COMPUTE
}

__global__ void ce_finalize(const float* __restrict__ sumexp,
                            const float* __restrict__ tgt,
                            const int* __restrict__ labels,
                            float* __restrict__ out)
{
    const int tid = threadIdx.x;
    float acc = 0.f, cnt = 0.f;
    for (int s = tid; s < SROWS; s += 256) {
        if (labels[s + 1] != IGNORE_INDEX) {
            acc += __logf(sumexp[s]) - tgt[s];
            cnt += 1.f;
        }
    }
#pragma unroll
    for (int off = 32; off > 0; off >>= 1) {
        acc += __shfl_down(acc, off);
        cnt += __shfl_down(cnt, off);
    }
    __shared__ float sa[4], sc[4];
    if ((tid & 63) == 0) { sa[tid >> 6] = acc; sc[tid >> 6] = cnt; }
    __syncthreads();
    if (tid == 0) {
        float a = sa[0] + sa[1] + sa[2] + sa[3];
        float c = sc[0] + sc[1] + sc[2] + sc[3];
        out[0] = a / fmaxf(c, 1.f);
    }
}

extern "C" void kernel_launch(void* const* d_in, const int* in_sizes, int n_in,
                              void* d_out, int out_size, void* d_ws, size_t ws_size,
                              hipStream_t stream)
{
    const float* emb    = (const float*)d_in[1];
    const float* W      = (const float*)d_in[2];
    const float* bias   = (const float*)d_in[3];
    const int*   labels = (const int*)d_in[4];

    float* wsf    = (float*)d_ws;
    float* sumexp = wsf;          // [2048]
    float* tgt    = wsf + 2048;   // [2048]

    hipMemsetAsync(d_ws, 0, 4096 * sizeof(float), stream);
    ce_fused_gemm<<<dim3(MT * NT), dim3(512), 0, stream>>>(emb, W, bias, labels, sumexp, tgt);
    ce_finalize<<<dim3(1), dim3(256), 0, stream>>>(sumexp, tgt, labels, (float*)d_out);
}

// Round 2
// 1379.651 us; speedup vs baseline: 1.2149x; 1.2149x over previous
//
#include <hip/hip_runtime.h>
#include <hip/hip_bf16.h>

#define IGNORE_INDEX (-100)

using f32x4  = __attribute__((ext_vector_type(4))) float;
using bf16x8 = __attribute__((ext_vector_type(8))) short;

constexpr int BM = 256, BN = 256;
constexpr int MT = 8;      // m tiles (2048 / 256)
constexpr int NT = 500;    // n tiles (128000 / 256)
constexpr int KT32 = 64;   // k tiles of 32 (2048 / 32)
constexpr int SROWS = 2047;
constexpr int DDIM = 2048;

// ws layout: [0,8KB) sumexp f32[2048] | [8KB,16KB) tgt f32[2048] | [16KB,+8.4MB) A bf16 | then W bf16
constexpr size_t WS_ACC_BYTES = 16384;
constexpr size_t WS_A_BYTES   = (size_t)2048 * 2048 * 2;
constexpr size_t WS_W_BYTES   = (size_t)128000 * 2048 * 2;
constexpr size_t WS_NEED      = WS_ACC_BYTES + WS_A_BYTES + WS_W_BYTES;

__device__ __forceinline__ unsigned cvt_pk_bf16(float lo, float hi) {
    unsigned r;
    asm("v_cvt_pk_bf16_f32 %0, %1, %2" : "=v"(r) : "v"(lo), "v"(hi));
    return r;
}

__device__ __forceinline__ void gload_lds16(const void* g, void* l) {
    __builtin_amdgcn_global_load_lds(
        (__attribute__((address_space(1))) void*)(g),
        (__attribute__((address_space(3))) void*)(l), 16, 0, 0);
}

// ---------------- prepass: fp32 -> bf16 (RNE via v_cvt_pk_bf16_f32) ----------------
__global__ __launch_bounds__(256)
void cvt_f32_bf16(const float* __restrict__ src, unsigned short* __restrict__ dst, size_t n8)
{
    size_t i = (size_t)blockIdx.x * 256 + threadIdx.x;
    const size_t stride = (size_t)gridDim.x * 256;
    for (; i < n8; i += stride) {
        const float4* s = (const float4*)(src + i * 8);
        float4 a = s[0], b = s[1];
        uint4 u;
        u.x = cvt_pk_bf16(a.x, a.y); u.y = cvt_pk_bf16(a.z, a.w);
        u.z = cvt_pk_bf16(b.x, b.y); u.w = cvt_pk_bf16(b.z, b.w);
        ((uint4*)dst)[i] = u;
    }
}

// ---------------- main fused GEMM + online CE epilogue (8-phase-style, bf16 in) ----------------
__global__ __launch_bounds__(512, 2)
void ce_gemm8p(const unsigned short* __restrict__ Abf,
               const unsigned short* __restrict__ Wbf,
               const float* __restrict__ bias,
               const int* __restrict__ labels,
               float* __restrict__ sumexp,
               float* __restrict__ tgt)
{
    // 3 buffer sets x (A[256][32] + B[256][32]) bf16 = 96 KiB
    __shared__ __align__(16) unsigned short lds[3 * 16384];

    const int bid = blockIdx.x;
    const int L = (bid & 7) * (MT * NT / 8) + (bid >> 3);
    const int n_tile = L >> 3;
    const int m_tile = L & 7;
    const int m_base = m_tile * BM;
    const int n_base = n_tile * BN;

    const int tid  = threadIdx.x;
    const int lane = tid & 63;
    const int wave = tid >> 6;
    const int wm = wave >> 2;   // 0..1
    const int wn = wave & 3;    // 0..3
    const int q = lane & 15;
    const int g = lane >> 4;    // 0..3
    // read-side swizzled chunk offset (shorts): chunk = g ^ ((row>>1)&3), row≡q (mod 8 blocks)
    const int lc = ((g ^ ((q >> 1) & 3)) << 3);

    // staging lane constants: lane covers row (l>>2), source chunk (l&3)^((l>>3)&3)
    const int srow    = lane >> 2;
    const int schunk8 = (((lane & 3) ^ ((lane >> 3) & 3)) << 3);

    f32x4 acc[8][4];
#pragma unroll
    for (int i = 0; i < 8; ++i)
#pragma unroll
        for (int j = 0; j < 4; ++j)
            acc[i][j] = (f32x4){0.f, 0.f, 0.f, 0.f};

    // waves 0-3 stage A slices (ids 0..15), waves 4-7 stage B slices (ids 16..31)
    auto STAGE = [&](int id, int set_, int kc) {
        const int R0 = (id & 15) << 4;           // 16-row slice base
        if (id < 16) {
            const unsigned short* src = Abf + (size_t)(m_base + R0 + srow) * DDIM + kc + schunk8;
            gload_lds16(src, &lds[set_ * 16384 + R0 * 32]);
        } else {
            const unsigned short* src = Wbf + (size_t)(n_base + R0 + srow) * DDIM + kc + schunk8;
            gload_lds16(src, &lds[set_ * 16384 + 8192 + R0 * 32]);
        }
    };

    // prologue: stage tile 0 -> set 0, tile 1 -> set 1; publish tile 0
#pragma unroll
    for (int i = 0; i < 4; ++i) STAGE(wave * 4 + i, 0, 0);
#pragma unroll
    for (int i = 0; i < 4; ++i) STAGE(wave * 4 + i, 1, 32);
    asm volatile("s_waitcnt vmcnt(4)" ::: "memory");
    asm volatile("s_barrier" ::: "memory");

    bf16x8 bfr[4];
    int set = 0, sset = 2;
    for (int t = 0; t < KT32; ++t) {
        const unsigned short* As_ = &lds[set * 16384];
        const unsigned short* Bs_ = As_ + 8192;
        const int abase = wm * 4096 + q * 32 + lc;
        const int bbase = wn * 2048 + q * 32 + lc;
        const int kc2 = (t + 2) * 32;
        const bool do_stage = (t < KT32 - 2);

        // ---- phase 0: mf 0..3 x nf 0..3 ----
        bf16x8 afr0[4];
#pragma unroll
        for (int nf = 0; nf < 4; ++nf) bfr[nf] = *(const bf16x8*)&Bs_[bbase + nf * 512];
#pragma unroll
        for (int m = 0; m < 4; ++m) afr0[m] = *(const bf16x8*)&As_[abase + m * 512];
        if (do_stage) { STAGE(wave * 4 + 0, sset, kc2); STAGE(wave * 4 + 1, sset, kc2); }
        asm volatile("s_barrier" ::: "memory");
        __builtin_amdgcn_s_setprio(1);
#pragma unroll
        for (int m = 0; m < 4; ++m)
#pragma unroll
            for (int nf = 0; nf < 4; ++nf)
                acc[m][nf] = __builtin_amdgcn_mfma_f32_16x16x32_bf16(afr0[m], bfr[nf], acc[m][nf], 0, 0, 0);
        __builtin_amdgcn_s_setprio(0);
        asm volatile("s_barrier" ::: "memory");

        // ---- phase 1: mf 4..7 x nf 0..3 (reuse bfr) ----
        bf16x8 afr1[4];
#pragma unroll
        for (int m = 0; m < 4; ++m) afr1[m] = *(const bf16x8*)&As_[abase + 2048 + m * 512];
        if (do_stage) { STAGE(wave * 4 + 2, sset, kc2); STAGE(wave * 4 + 3, sset, kc2); }
        asm volatile("s_barrier" ::: "memory");
        __builtin_amdgcn_s_setprio(1);
#pragma unroll
        for (int m = 0; m < 4; ++m)
#pragma unroll
            for (int nf = 0; nf < 4; ++nf)
                acc[4 + m][nf] = __builtin_amdgcn_mfma_f32_16x16x32_bf16(afr1[m], bfr[nf], acc[4 + m][nf], 0, 0, 0);
        __builtin_amdgcn_s_setprio(0);
        // counted wait: keep newest 4 loads (tile t+2) in flight; tile t+1 guaranteed landed
        if (t < KT32 - 2)       asm volatile("s_waitcnt vmcnt(4)" ::: "memory");
        else if (t == KT32 - 2) asm volatile("s_waitcnt vmcnt(0)" ::: "memory");
        asm volatile("s_barrier" ::: "memory");

        set  = (set  == 2) ? 0 : set  + 1;
        sset = (sset == 2) ? 0 : sset + 1;
    }

    // ---- epilogue: bias + exp + row-sum + target gather ----
    const int grow_base = m_base + wm * 128;
    const int gcol_base = n_base + wn * 64;
#pragma unroll
    for (int mf = 0; mf < 8; ++mf) {
        const int rb = grow_base + mf * 16 + g * 4;
        int lbl[4];
#pragma unroll
        for (int r = 0; r < 4; ++r)
            lbl[r] = (rb + r < SROWS) ? labels[rb + r + 1] : -1;
        float rsum[4] = {0.f, 0.f, 0.f, 0.f};
#pragma unroll
        for (int nf = 0; nf < 4; ++nf) {
            const int gc = gcol_base + nf * 16 + q;
            const float bz = bias[gc];
            const f32x4 v = acc[mf][nf];
#pragma unroll
            for (int r = 0; r < 4; ++r) {
                const float s = v[r] + bz;
                if (lbl[r] == gc) atomicAdd(&tgt[rb + r], s);
                rsum[r] += __expf(s);
            }
        }
#pragma unroll
        for (int r = 0; r < 4; ++r) {
#pragma unroll
            for (int off = 1; off < 16; off <<= 1)
                rsum[r] += __shfl_xor(rsum[r], off);
        }
        if (q == 0) {
#pragma unroll
            for (int r = 0; r < 4; ++r)
                if (rb + r < SROWS) atomicAdd(&sumexp[rb + r], rsum[r]);
        }
    }
}

// ---------------- fallback (round-1 kernel): fp32 in, reg-staged cvt ----------------
__global__ __launch_bounds__(512, 2)
void ce_fused_gemm(const float* __restrict__ emb,
                   const float* __restrict__ W,
                   const float* __restrict__ bias,
                   const int* __restrict__ labels,
                   float* __restrict__ sumexp,
                   float* __restrict__ tgt)
{
    constexpr int BK = 64;
    constexpr int KT = 32;
    __shared__ __align__(16) unsigned short As[2][BM * BK];
    __shared__ __align__(16) unsigned short Bs[2][BN * BK];

    const int bid = blockIdx.x;
    const int L = (bid & 7) * (MT * NT / 8) + (bid >> 3);
    const int n_tile = L >> 3;
    const int m_tile = L & 7;
    const size_t m_base = (size_t)m_tile * BM;
    const size_t n_base = (size_t)n_tile * BN;

    const int tid  = threadIdx.x;
    const int lane = tid & 63;
    const int wave = tid >> 6;
    const int wm = wave >> 2;
    const int wn = wave & 3;
    const int q = lane & 15;
    const int g = lane >> 4;
    const int r0 = tid >> 3;
    const int kg = tid & 7;

    float4 stA[4][2], stB[4][2];
    f32x4 acc[8][4];
#pragma unroll
    for (int i = 0; i < 8; ++i)
#pragma unroll
        for (int j = 0; j < 4; ++j)
            acc[i][j] = (f32x4){0.f, 0.f, 0.f, 0.f};

    const float* Ab = emb + m_base * DDIM + (size_t)kg * 8;
    const float* Bb = W   + n_base * DDIM + (size_t)kg * 8;

#define STAGE_LOAD(kt_) { \
    const size_t ko = (size_t)(kt_) * BK; \
    _Pragma("unroll") \
    for (int p = 0; p < 4; ++p) { \
        const int row = r0 + p * 64; \
        const float4* pa = (const float4*)(Ab + (size_t)row * DDIM + ko); \
        stA[p][0] = pa[0]; stA[p][1] = pa[1]; \
        const float4* pb = (const float4*)(Bb + (size_t)row * DDIM + ko); \
        stB[p][0] = pb[0]; stB[p][1] = pb[1]; \
    } }

#define STAGE_WRITE(bf_) { \
    _Pragma("unroll") \
    for (int p = 0; p < 4; ++p) { \
        const int row = r0 + p * 64; \
        const int sw = (kg * 8) ^ ((row & 7) << 3); \
        uint4 ua; \
        ua.x = cvt_pk_bf16(stA[p][0].x, stA[p][0].y); \
        ua.y = cvt_pk_bf16(stA[p][0].z, stA[p][0].w); \
        ua.z = cvt_pk_bf16(stA[p][1].x, stA[p][1].y); \
        ua.w = cvt_pk_bf16(stA[p][1].z, stA[p][1].w); \
        *(uint4*)&As[bf_][row * BK + sw] = ua; \
        uint4 ub; \
        ub.x = cvt_pk_bf16(stB[p][0].x, stB[p][0].y); \
        ub.y = cvt_pk_bf16(stB[p][0].z, stB[p][0].w); \
        ub.z = cvt_pk_bf16(stB[p][1].x, stB[p][1].y); \
        ub.w = cvt_pk_bf16(stB[p][1].z, stB[p][1].w); \
        *(uint4*)&Bs[bf_][row * BK + sw] = ub; \
    } }

#define COMPUTE(bf_) { \
    _Pragma("unroll") \
    for (int kh = 0; kh < 2; ++kh) { \
        const int c = kh * 32 + g * 8; \
        bf16x8 bfr[4]; \
        _Pragma("unroll") \
        for (int nf = 0; nf < 4; ++nf) { \
            const int rr = wn * 64 + nf * 16 + q; \
            bfr[nf] = *(const bf16x8*)&Bs[bf_][rr * BK + (c ^ ((rr & 7) << 3))]; \
        } \
        _Pragma("unroll") \
        for (int mf = 0; mf < 8; ++mf) { \
            const int rr = wm * 128 + mf * 16 + q; \
            bf16x8 afr = *(const bf16x8*)&As[bf_][rr * BK + (c ^ ((rr & 7) << 3))]; \
            _Pragma("unroll") \
            for (int nf = 0; nf < 4; ++nf) \
                acc[mf][nf] = __builtin_amdgcn_mfma_f32_16x16x32_bf16(afr, bfr[nf], acc[mf][nf], 0, 0, 0); \
        } \
    } }

    STAGE_LOAD(0);
    STAGE_WRITE(0);
    __syncthreads();

    int buf = 0;
    for (int kt = 0; kt < KT; ++kt) {
        if (kt + 1 < KT) STAGE_LOAD(kt + 1);
        COMPUTE(buf);
        if (kt + 1 < KT) STAGE_WRITE(buf ^ 1);
        __syncthreads();
        buf ^= 1;
    }

    const int grow_base = (int)m_base + wm * 128;
    const int gcol_base = (int)n_base + wn * 64;
#pragma unroll
    for (int mf = 0; mf < 8; ++mf) {
        const int rb = grow_base + mf * 16 + g * 4;
        int lbl[4];
#pragma unroll
        for (int r = 0; r < 4; ++r)
            lbl[r] = (rb + r < SROWS) ? labels[rb + r + 1] : -1;
        float rsum[4] = {0.f, 0.f, 0.f, 0.f};
#pragma unroll
        for (int nf = 0; nf < 4; ++nf) {
            const int gc = gcol_base + nf * 16 + q;
            const float bz = bias[gc];
            const f32x4 v = acc[mf][nf];
#pragma unroll
            for (int r = 0; r < 4; ++r) {
                const float s = v[r] + bz;
                if (lbl[r] == gc) atomicAdd(&tgt[rb + r], s);
                rsum[r] += __expf(s);
            }
        }
#pragma unroll
        for (int r = 0; r < 4; ++r) {
#pragma unroll
            for (int off = 1; off < 16; off <<= 1)
                rsum[r] += __shfl_xor(rsum[r], off);
        }
        if (q == 0) {
#pragma unroll
            for (int r = 0; r < 4; ++r)
                if (rb + r < SROWS) atomicAdd(&sumexp[rb + r], rsum[r]);
        }
    }
#undef STAGE_LOAD
#undef STAGE_WRITE
#undef COMPUTE
}

__global__ void ce_finalize(const float* __restrict__ sumexp,
                            const float* __restrict__ tgt,
                            const int* __restrict__ labels,
                            float* __restrict__ out)
{
    const int tid = threadIdx.x;
    float acc = 0.f, cnt = 0.f;
    for (int s = tid; s < SROWS; s += 256) {
        if (labels[s + 1] != IGNORE_INDEX) {
            acc += __logf(sumexp[s]) - tgt[s];
            cnt += 1.f;
        }
    }
#pragma unroll
    for (int off = 32; off > 0; off >>= 1) {
        acc += __shfl_down(acc, off);
        cnt += __shfl_down(cnt, off);
    }
    __shared__ float sa[4], sc[4];
    if ((tid & 63) == 0) { sa[tid >> 6] = acc; sc[tid >> 6] = cnt; }
    __syncthreads();
    if (tid == 0) {
        float a = sa[0] + sa[1] + sa[2] + sa[3];
        float c = sc[0] + sc[1] + sc[2] + sc[3];
        out[0] = a / fmaxf(c, 1.f);
    }
}

extern "C" void kernel_launch(void* const* d_in, const int* in_sizes, int n_in,
                              void* d_out, int out_size, void* d_ws, size_t ws_size,
                              hipStream_t stream)
{
    const float* emb    = (const float*)d_in[1];
    const float* W      = (const float*)d_in[2];
    const float* bias   = (const float*)d_in[3];
    const int*   labels = (const int*)d_in[4];

    float* wsf    = (float*)d_ws;
    float* sumexp = wsf;
    float* tgt    = wsf + 2048;

    hipMemsetAsync(d_ws, 0, WS_ACC_BYTES, stream);

    if (ws_size >= WS_NEED) {
        unsigned short* Abf = (unsigned short*)((char*)d_ws + WS_ACC_BYTES);
        unsigned short* Wbf = (unsigned short*)((char*)d_ws + WS_ACC_BYTES + WS_A_BYTES);
        cvt_f32_bf16<<<dim3(2048), dim3(256), 0, stream>>>(W, Wbf, (size_t)128000 * 2048 / 8);
        cvt_f32_bf16<<<dim3(256),  dim3(256), 0, stream>>>(emb, Abf, (size_t)2048 * 2048 / 8);
        ce_gemm8p<<<dim3(MT * NT), dim3(512), 0, stream>>>(Abf, Wbf, bias, labels, sumexp, tgt);
    } else {
        ce_fused_gemm<<<dim3(MT * NT), dim3(512), 0, stream>>>(emb, W, bias, labels, sumexp, tgt);
    }
    ce_finalize<<<dim3(1), dim3(256), 0, stream>>>(sumexp, tgt, labels, (float*)d_out);
}